// Round 10
// baseline (287.764 us; speedup 1.0000x reference)
//
#include <hip/hip_runtime.h>
#include <math.h>

// Problem constants (match reference)
constexpr int EN = 200000;   // edges == nodes
constexpr int D  = 128;      // embedding dim
constexpr int R  = 4;        // relation types
constexpr float NEG = 0.01f;

constexpr int NBLKE = (EN + 255) / 256;   // 782 histogram blocks
constexpr int NPREP = 66;                 // 16896 prep threads
constexpr int NCH   = (EN + 1023) / 1024; // 196 scan chunks

static inline int ceil_div(int a, int b) { return (a + b - 1) / b; }

typedef __attribute__((ext_vector_type(8))) __bf16 bf16x8;
typedef __attribute__((ext_vector_type(4))) float f32x4;

// ---------- bf16 helpers (RNE) ----------
__device__ __forceinline__ unsigned short f2bf(float f) {
    union { float f; unsigned u; } v; v.f = f;
    unsigned u = v.u + 0x7fffu + ((v.u >> 16) & 1u);
    return (unsigned short)(u >> 16);
}
__device__ __forceinline__ unsigned pack2bf(float a, float b) {
    return (unsigned)f2bf(a) | ((unsigned)f2bf(b) << 16);
}
__device__ __forceinline__ float bflo(unsigned m) { return __uint_as_float(m << 16); }
__device__ __forceinline__ float bfhi(unsigned m) { return __uint_as_float(m & 0xffff0000u); }

// ---------- W pre-swizzle to MFMA A-frag bf16 ----------
__device__ __forceinline__ void wswz_one(const float* __restrict__ w,
                                         unsigned short* __restrict__ wsw, int t) {
    int lane = t & 63, mt = (t >> 6) & 7, s = (t >> 9) & 3, r = t >> 11;
    int q = lane >> 4, n = mt * 16 + (lane & 15);
    union { unsigned short us[8]; uint4 u4; } o;
    #pragma unroll
    for (int j = 0; j < 8; ++j) {
        int k = s * 32 + q * 8 + j;
        o.us[j] = f2bf(w[((size_t)r * D + k) * D + n]);
    }
    *(uint4*)(wsw + (size_t)t * 8) = o.u4;
}

// ---------- histogram (col degree + relation counts) + W prep, one dispatch ----------
__global__ void k_cntprep(const int* __restrict__ col, const int* __restrict__ etyp,
                          const float* __restrict__ w1, const float* __restrict__ w2,
                          const float* __restrict__ w3,
                          int* __restrict__ cnt, int* __restrict__ rcnt,
                          unsigned short* __restrict__ w2b, unsigned short* __restrict__ w3b,
                          float* __restrict__ s1) {
    const int b = blockIdx.x, t = threadIdx.x;
    if (b < NBLKE) {
        __shared__ int lr[R];
        if (t < R) lr[t] = 0;
        __syncthreads();
        int e = b * 256 + t;
        if (e < EN) {
            atomicAdd(&cnt[col[e]], 1);
            atomicAdd(&lr[etyp[e]], 1);
        }
        __syncthreads();
        if (t < R && lr[t]) atomicAdd(&rcnt[t], lr[t]);
    } else {
        int g = (b - NBLKE) * 256 + t;     // 0..16895
        if (g < 8192) {
            wswz_one(w2, w2b, g);
        } else if (g < 16384) {
            wswz_one(w3, w3b, g - 8192);
        } else if (g < 16896) {
            int t2 = g - 16384;            // 0..511: colsum(W1)
            int r = t2 >> 7, j = t2 & (D - 1);
            float s = 0.f;
            for (int k = 0; k < D; ++k) s += w1[((r << 7) + k) * D + j];
            s1[t2] = s;
        }
    }
}

// ---------- scan (single dispatch): direct global prefix + col_start + ccur + dinv
//            + crel zeroing, block0 extras ----------
// Each block computes base0 = sum(cnt[0 .. bid*1024)) directly from L2-resident cnt
// (78 MB aggregate L2 reads ~ 2-3 us) -> no scanA dispatch, no part[] round trip.
__global__ void k_scan(const int* __restrict__ cnt, const int* __restrict__ rcnt,
                       int* __restrict__ rbase, int* __restrict__ cursor,
                       int* __restrict__ col_start, int* __restrict__ ccur,
                       float* __restrict__ dinv, float* __restrict__ crel,
                       int4* __restrict__ bk_pack) {
    __shared__ int sm[256];
    __shared__ int sbase[R + 1];
    __shared__ int scnt[R];
    int t = threadIdx.x, bid = blockIdx.x;
    // zero crel (consumer is k_bucket, next dispatch): 200000 int4, ~4 per thread
    {
        int4* cz = (int4*)crel;
        int4 z = make_int4(0, 0, 0, 0);
        for (int i = bid * 256 + t; i < EN; i += NCH * 256) cz[i] = z;
    }
    // phase 1: direct prefix over preceding chunks (int4 loads of cnt)
    int s = 0;
    {
        const int4* c4 = (const int4*)cnt;
        const int lim4 = bid * 256;       // bid*1024 ints
        for (int i = t; i < lim4; i += 256) {
            int4 v = c4[i];
            s += v.x + v.y + v.z + v.w;
        }
    }
    sm[t] = s; __syncthreads();
    for (int off = 128; off > 0; off >>= 1) {
        if (t < off) sm[t] += sm[t + off];
        __syncthreads();
    }
    const int base0 = sm[0];
    __syncthreads();                      // protect sm before reuse
    // phase 2: intra-chunk exclusive positions (+ dinv in the same cnt pass)
    int base = bid * 1024 + t * 4;
    int v[4]; s = 0;
    #pragma unroll
    for (int i = 0; i < 4; ++i) {
        int idx = base + i;
        v[i] = (idx < EN) ? cnt[idx] : 0;
        s += v[i];
        if (idx < EN) dinv[idx] = (v[i] > 0) ? rsqrtf((float)v[i]) : 0.f;
    }
    sm[t] = s; __syncthreads();
    for (int off = 1; off < 256; off <<= 1) {
        int u = 0; if (t >= off) u = sm[t - off];
        __syncthreads(); sm[t] += u; __syncthreads();
    }
    int ex = ((t > 0) ? sm[t - 1] : 0) + base0;
    #pragma unroll
    for (int i = 0; i < 4; ++i) {
        int idx = base + i;
        if (idx < EN) { col_start[idx] = ex; ex += v[i]; ccur[idx] = 0; }
    }
    // block 0 extras: 16-padded relation bases + bk pad-init
    if (bid == 0) {
        if (t == 0) {
            int acc = 0;
            for (int r = 0; r < R; ++r) {
                sbase[r] = acc; rbase[r] = acc; cursor[r] = acc;
                int c0 = rcnt[r]; scnt[r] = c0;
                acc += (c0 + 15) & ~15;   // 16-aligned bucket regions
            }
            sbase[R] = acc; rbase[R] = acc;
            col_start[EN] = EN;
        }
        __syncthreads();
        // pads: row=0 (safe gather), dst=EN (dump row), coef=0 (no contribution)
        for (int r = 0; r < R; ++r) {
            int ps = sbase[r] + scnt[r], pe = sbase[r + 1];
            for (int i = ps + t; i < pe; i += 256)
                bk_pack[i] = make_int4(0, EN, 0, 0);
        }
    }
}

// ---------- bucket by relation (16-padded) + col-sorted slot + coef + crel ----------
__global__ void k_bucket(const int* __restrict__ row, const int* __restrict__ col,
                         const int* __restrict__ etype, const float* __restrict__ attr,
                         const float* __restrict__ dinv, const int* __restrict__ col_start,
                         int* __restrict__ cursor, int* __restrict__ ccur,
                         int4* __restrict__ bk_pack, float* __restrict__ crel) {
    __shared__ int lcnt[R];
    __shared__ int lbase[R];
    int t = threadIdx.x;
    if (t < R) lcnt[t] = 0;
    __syncthreads();
    int e = blockIdx.x * 256 + t;
    int r = 0, rank = 0, c = 0, rw = 0;
    float cf = 0.f;
    if (e < EN) {
        r = etype[e];
        rank = atomicAdd(&lcnt[r], 1);
        c = col[e]; rw = row[e];
        cf = attr[e] * dinv[rw] * dinv[c];
    }
    __syncthreads();
    if (t < R) lbase[t] = lcnt[t] ? atomicAdd(&cursor[t], lcnt[t]) : 0;
    __syncthreads();
    if (e < EN) {
        int pos = lbase[r] + rank;                       // padded relation bucket
        int sp = col_start[c] + atomicAdd(&ccur[c], 1);  // col-sorted slot
        bk_pack[pos] = make_int4(rw, sp, __float_as_int(cf), 0);
        atomicAdd(&crel[c * 4 + r], cf);
    }
}

// ================= MFMA GEMM: flat 1-D tile grid over padded buckets =================
// LAYER 2: B-frags = z1 on the fly from crel[srow] (16 B) vs LDS s1/b1; writes msg2.
// LAYER 3: B-frags = z2 on the fly from msg2 segment [col_start[srow],col_start[srow+1])
//          (col-sorted => contiguous; E[deg]=1) + b2 + leaky; writes msg3.
template<int LAYER>
__global__ __launch_bounds__(256)
void k_gemm(const unsigned short* __restrict__ msrc,    // LAYER 3: msg2
            const unsigned short* __restrict__ wsw,
            const int4* __restrict__ bk_pack, const int* __restrict__ rbase,
            const int* __restrict__ col_start,
            const float* __restrict__ crel, const float* __restrict__ s1g,
            const float* __restrict__ b1, const float* __restrict__ b2,
            unsigned short* __restrict__ mdst) {
    const int t = threadIdx.x;
    __shared__ unsigned short xpose[4][16 * 144];   // 18 KB; wave-private regions
    __shared__ float ls1[R * D];
    __shared__ float lb[D];                         // b1 (L2) or b2 (L3)
    if constexpr (LAYER == 2) {
        ls1[t] = s1g[t];
        ls1[t + 256] = s1g[t + 256];
        if (t < D) lb[t] = b1[t];
    } else {
        if (t < D) lb[t] = b2[t];
    }
    __syncthreads();                        // before any wave can early-exit
    const int tile = blockIdx.x * 4 + (t >> 6);
    const int e16 = tile * 16;
    if (e16 >= rbase[R]) return;            // wave-uniform early exit (tail only)
    const int r = (e16 >= rbase[1]) + (e16 >= rbase[2]) + (e16 >= rbase[3]);
    const int l = t & 63, q = l >> 4, n16 = l & 15;
    const int p = e16 + n16;                // always in-bounds (padded buckets)
    const int4 bk = bk_pack[p];             // one 16 B load: {row, dst, coef, -}
    const int srow = bk.x;
    const int dp = bk.y;
    const float cf = __int_as_float(bk.z);

    // B-frags: x[edge][k]; lane covers k = s*32 + q*8 .. +8
    bf16x8 xf[4];
    if constexpr (LAYER == 2) {
        const float4 cr = ((const float4*)crel)[srow];   // 16 B instead of 256 B row
        #pragma unroll
        for (int s = 0; s < 4; ++s) {
            union { unsigned short us[8]; bf16x8 v; } o;
            #pragma unroll
            for (int j = 0; j < 8; ++j) {
                int k = s * 32 + q * 8 + j;
                float xv = lb[k] + cr.x * ls1[k] + cr.y * ls1[D + k]
                         + cr.z * ls1[2 * D + k] + cr.w * ls1[3 * D + k];
                xv = (xv > 0.f) ? xv : NEG * xv;
                o.us[j] = f2bf(xv);
            }
            xf[s] = o.v;
        }
    } else {
        // z2 on the fly: fp32 segment sum over msg2 (pads: srow=0, harmless)
        const int st = col_start[srow], en = col_start[srow + 1];
        float za[32];
        #pragma unroll
        for (int i = 0; i < 32; ++i) za[i] = 0.f;
        for (int p2 = st; p2 < en; ++p2) {
            const unsigned short* mrow = msrc + (size_t)p2 * D + q * 8;
            #pragma unroll
            for (int s = 0; s < 4; ++s) {
                uint4 u = *(const uint4*)(mrow + s * 32);
                za[s * 8 + 0] += bflo(u.x); za[s * 8 + 1] += bfhi(u.x);
                za[s * 8 + 2] += bflo(u.y); za[s * 8 + 3] += bfhi(u.y);
                za[s * 8 + 4] += bflo(u.z); za[s * 8 + 5] += bfhi(u.z);
                za[s * 8 + 6] += bflo(u.w); za[s * 8 + 7] += bfhi(u.w);
            }
        }
        #pragma unroll
        for (int s = 0; s < 4; ++s) {
            union { unsigned short us[8]; bf16x8 v; } o;
            #pragma unroll
            for (int j = 0; j < 8; ++j) {
                float xv = za[s * 8 + j] + lb[s * 32 + q * 8 + j];
                xv = (xv > 0.f) ? xv : NEG * xv;
                o.us[j] = f2bf(xv);
            }
            xf[s] = o.v;
        }
    }

    // A-frags: swizzled W, L1/L2-resident
    const unsigned short* wr = wsw + ((size_t)r * 2048 + l) * 8;

    f32x4 acc[8];
    #pragma unroll
    for (int mt = 0; mt < 8; ++mt) acc[mt] = (f32x4){0.f, 0.f, 0.f, 0.f};

    #pragma unroll
    for (int s = 0; s < 4; ++s) {
        #pragma unroll
        for (int mt = 0; mt < 8; ++mt) {
            bf16x8 wf = *(const bf16x8*)(wr + (size_t)(s * 512 + mt * 64) * 8);
            acc[mt] = __builtin_amdgcn_mfma_f32_16x16x32_bf16(wf, xf[s], acc[mt], 0, 0, 0);
        }
    }

    // epilogue: scale, pack, transpose through wave-private LDS, coalesced store
    unsigned short* lbuf = xpose[t >> 6];
    #pragma unroll
    for (int mt = 0; mt < 8; ++mt) {
        uint2 u;
        u.x = pack2bf(acc[mt].x * cf, acc[mt].y * cf);
        u.y = pack2bf(acc[mt].z * cf, acc[mt].w * cf);
        *(uint2*)&lbuf[n16 * 144 + mt * 16 + q * 4] = u;
    }
    #pragma unroll
    for (int ro = 0; ro < 4; ++ro) {
        int e = ro * 4 + q;
        uint4 v = *(const uint4*)&lbuf[e * 144 + n16 * 8];
        int rdp = __shfl(dp, e);
        *(uint4*)(mdst + (size_t)rdp * D + n16 * 8) = v;
    }
}

// ================= final combine: one pass over msg2+msg3 (same segments) =================
// dout = (1 + z1(crel) + z2(msg2) + z3(msg3)) * 0.25; z1,z2 fp32 (never materialized)
__global__ void k_agg3(const unsigned* __restrict__ m2, const unsigned* __restrict__ m3,
                       const float* __restrict__ b2v, const float* __restrict__ b3v,
                       const int* __restrict__ col_start,
                       const float* __restrict__ crel, const float* __restrict__ s1g,
                       const float* __restrict__ b1, float* __restrict__ dout) {
    __shared__ float ls1[R * D];
    __shared__ float lb1[D], lb2[D], lb3[D];
    int t = threadIdx.x;
    ls1[t] = s1g[t];
    ls1[t + 256] = s1g[t + 256];
    if (t < D) { lb1[t] = b1[t]; lb2[t] = b2v[t]; lb3[t] = b3v[t]; }
    __syncthreads();
    int lane = t & 63;
    for (int c = blockIdx.x * 4 + (t >> 6); c < EN; c += gridDim.x * 4) {
        int st = col_start[c], pe = col_start[c + 1];
        float s20 = 0.f, s21 = 0.f, s30 = 0.f, s31 = 0.f;
        for (int p = st; p < pe; ++p) {
            unsigned u2 = m2[(size_t)p * 64 + lane];
            unsigned u3 = m3[(size_t)p * 64 + lane];
            s20 += bflo(u2); s21 += bfhi(u2);
            s30 += bflo(u3); s31 += bfhi(u3);
        }
        int d0 = lane * 2, d1 = d0 + 1;
        float z2a = s20 + lb2[d0], z2b = s21 + lb2[d1];
        z2a = (z2a > 0.f) ? z2a : NEG * z2a;
        z2b = (z2b > 0.f) ? z2b : NEG * z2b;
        float z3a = s30 + lb3[d0], z3b = s31 + lb3[d1];
        z3a = (z3a > 0.f) ? z3a : NEG * z3a;
        z3b = (z3b > 0.f) ? z3b : NEG * z3b;
        float4 cr = ((const float4*)crel)[c];   // wave-uniform 16 B
        float z1a = lb1[d0] + cr.x * ls1[d0] + cr.y * ls1[D + d0]
                  + cr.z * ls1[2 * D + d0] + cr.w * ls1[3 * D + d0];
        float z1b = lb1[d1] + cr.x * ls1[d1] + cr.y * ls1[D + d1]
                  + cr.z * ls1[2 * D + d1] + cr.w * ls1[3 * D + d1];
        z1a = (z1a > 0.f) ? z1a : NEG * z1a;
        z1b = (z1b > 0.f) ? z1b : NEG * z1b;
        float2 o;
        o.x = (1.f + z1a + z2a + z3a) * 0.25f;
        o.y = (1.f + z1b + z2b + z3b) * 0.25f;
        ((float2*)(dout + (size_t)c * D))[lane] = o;
    }
}

extern "C" void kernel_launch(void* const* d_in, const int* in_sizes, int n_in,
                              void* d_out, int out_size, void* d_ws, size_t ws_size,
                              hipStream_t stream) {
    const int*   eidx = (const int*)d_in[0];     // [2, E]
    const int*   row  = eidx;
    const int*   col  = eidx + EN;
    const int*   etyp = (const int*)d_in[1];
    const float* attr = (const float*)d_in[2];
    const float* w1   = (const float*)d_in[3];
    const float* b1   = (const float*)d_in[4];
    const float* w2   = (const float*)d_in[5];
    const float* b2   = (const float*)d_in[6];
    const float* w3   = (const float*)d_in[7];
    const float* b3   = (const float*)d_in[8];
    float* dout = (float*)d_out;

    // workspace layout (~115 MB; ws is ~409.6 MB per harness poison size)
    char* wsb = (char*)d_ws;
    size_t off = 0;
    unsigned short* msg2 = (unsigned short*)(wsb + off); off += (size_t)(EN + 1) * D * 2 + 512;
    unsigned short* msg3 = (unsigned short*)(wsb + off); off += (size_t)(EN + 1) * D * 2 + 512;
    int*   col_start = (int*)(wsb + off); off += 800032;
    int*   cnt       = (int*)(wsb + off); off += (size_t)EN * 4;
    int*   rcnt      = (int*)(wsb + off); off += 16;          // contiguous after cnt
    float* crel      = (float*)(wsb + off); off += (size_t)EN * 16;
    int4*  bk_pack   = (int4*)(wsb + off); off += (size_t)(EN + 64) * 16;
    float* dinv      = (float*)(wsb + off); off += (size_t)EN * 4;
    unsigned short* w2b = (unsigned short*)(wsb + off); off += 131072;
    unsigned short* w3b = (unsigned short*)(wsb + off); off += 131072;
    int*   rbase     = (int*)(wsb + off); off += 32;
    int*   cursor    = (int*)(wsb + off); off += 16;
    float* s1        = (float*)(wsb + off); off += (size_t)R * D * 4;
    int*   ccur      = (int*)msg2;   // aliased: msg2 not live until GEMM layer 2

    dim3 blk(256);

    // zero cnt + rcnt only (0.8 MB); crel zeroed inside k_scan
    hipMemsetAsync(cnt, 0, (size_t)EN * 4 + 16, stream);
    // histogram + W prep
    k_cntprep<<<NBLKE + NPREP, blk, 0, stream>>>(col, etyp, w1, w2, w3,
                                                 cnt, rcnt, w2b, w3b, s1);
    // single scan dispatch: direct prefix + col_start + ccur + dinv + crel zero + extras
    k_scan<<<NCH, blk, 0, stream>>>(cnt, rcnt, rbase, cursor, col_start,
                                    ccur, dinv, crel, bk_pack);
    // bucket + col-sort placement + coef + crel accumulation
    k_bucket<<<NBLKE, blk, 0, stream>>>(row, col, etyp, attr, dinv, col_start,
                                        cursor, ccur, bk_pack, crel);

    // layers 2,3: flat-tile GEMM (z1, z2 both on the fly) + single final combine
    const int nTiles = ceil_div(EN + 64, 16);
    const int gB = ceil_div(nTiles, 4);              // 3126 blocks
    k_gemm<2><<<gB, blk, 0, stream>>>(nullptr, w2b, bk_pack, rbase, col_start,
                                      crel, s1, b1, b2, msg2);
    k_gemm<3><<<gB, blk, 0, stream>>>(msg2, w3b, bk_pack, rbase, col_start,
                                      crel, s1, b1, b2, msg3);
    k_agg3<<<2048, blk, 0, stream>>>((const unsigned*)msg2, (const unsigned*)msg3,
                                     b2, b3, col_start, crel, s1, b1, dout);
}

// Round 11
// 265.304 us; speedup vs baseline: 1.0847x; 1.0847x over previous
//
#include <hip/hip_runtime.h>
#include <math.h>

// Problem constants (match reference)
constexpr int EN = 200000;   // edges == nodes
constexpr int D  = 128;      // embedding dim
constexpr int R  = 4;        // relation types
constexpr float NEG = 0.01f;

constexpr int NBLKE = (EN + 255) / 256;   // 782 histogram blocks
constexpr int NPREP = 66;                 // 16896 prep threads
constexpr int NCH   = (EN + 1023) / 1024; // 196 scan chunks (must be <= 256)

static inline int ceil_div(int a, int b) { return (a + b - 1) / b; }

typedef __attribute__((ext_vector_type(8))) __bf16 bf16x8;
typedef __attribute__((ext_vector_type(4))) float f32x4;

// ---------- bf16 helpers (RNE) ----------
__device__ __forceinline__ unsigned short f2bf(float f) {
    union { float f; unsigned u; } v; v.f = f;
    unsigned u = v.u + 0x7fffu + ((v.u >> 16) & 1u);
    return (unsigned short)(u >> 16);
}
__device__ __forceinline__ unsigned pack2bf(float a, float b) {
    return (unsigned)f2bf(a) | ((unsigned)f2bf(b) << 16);
}
__device__ __forceinline__ float bflo(unsigned m) { return __uint_as_float(m << 16); }
__device__ __forceinline__ float bfhi(unsigned m) { return __uint_as_float(m & 0xffff0000u); }

// ---------- W pre-swizzle to MFMA A-frag bf16 ----------
__device__ __forceinline__ void wswz_one(const float* __restrict__ w,
                                         unsigned short* __restrict__ wsw, int t) {
    int lane = t & 63, mt = (t >> 6) & 7, s = (t >> 9) & 3, r = t >> 11;
    int q = lane >> 4, n = mt * 16 + (lane & 15);
    union { unsigned short us[8]; uint4 u4; } o;
    #pragma unroll
    for (int j = 0; j < 8; ++j) {
        int k = s * 32 + q * 8 + j;
        o.us[j] = f2bf(w[((size_t)r * D + k) * D + n]);
    }
    *(uint4*)(wsw + (size_t)t * 8) = o.u4;
}

// ---------- histogram (col degree + relation counts) + W prep, one dispatch ----------
__global__ void k_cntprep(const int* __restrict__ col, const int* __restrict__ etyp,
                          const float* __restrict__ w1, const float* __restrict__ w2,
                          const float* __restrict__ w3,
                          int* __restrict__ cnt, int* __restrict__ rcnt,
                          unsigned short* __restrict__ w2b, unsigned short* __restrict__ w3b,
                          float* __restrict__ s1) {
    const int b = blockIdx.x, t = threadIdx.x;
    if (b < NBLKE) {
        __shared__ int lr[R];
        if (t < R) lr[t] = 0;
        __syncthreads();
        int e = b * 256 + t;
        if (e < EN) {
            atomicAdd(&cnt[col[e]], 1);
            atomicAdd(&lr[etyp[e]], 1);
        }
        __syncthreads();
        if (t < R && lr[t]) atomicAdd(&rcnt[t], lr[t]);
    } else {
        int g = (b - NBLKE) * 256 + t;     // 0..16895
        if (g < 8192) {
            wswz_one(w2, w2b, g);
        } else if (g < 16384) {
            wswz_one(w3, w3b, g - 8192);
        } else if (g < 16896) {
            int t2 = g - 16384;            // 0..511: colsum(W1)
            int r = t2 >> 7, j = t2 & (D - 1);
            float s = 0.f;
            for (int k = 0; k < D; ++k) s += w1[((r << 7) + k) * D + j];
            s1[t2] = s;
        }
    }
}

// ---------- scan A: per-1024-chunk sums + dinv = rsqrt(deg) (free in same pass) ----------
__global__ void k_scanA(const int* __restrict__ cnt, int* __restrict__ part,
                        float* __restrict__ dinv) {
    __shared__ int sm[256];
    int t = threadIdx.x;
    int base = blockIdx.x * 1024 + t * 4;
    int s = 0;
    #pragma unroll
    for (int i = 0; i < 4; ++i) {
        int idx = base + i;
        if (idx < EN) {
            int v = cnt[idx];
            s += v;
            dinv[idx] = (v > 0) ? rsqrtf((float)v) : 0.f;
        }
    }
    sm[t] = s; __syncthreads();
    for (int off = 128; off > 0; off >>= 1) {
        if (t < off) sm[t] += sm[t + off];
        __syncthreads();
    }
    if (t == 0) part[blockIdx.x] = sm[0];
}

// ---------- scan B: redundant global rescan + col_start + ccur, block0 extras ----------
__global__ void k_scanB(const int* __restrict__ cnt, const int* __restrict__ part,
                        const int* __restrict__ rcnt,
                        int* __restrict__ rbase, int* __restrict__ cursor,
                        int* __restrict__ col_start, int* __restrict__ ccur,
                        int4* __restrict__ bk_pack) {
    __shared__ int sm[256];
    __shared__ int sbase[R + 1];
    __shared__ int scnt[R];
    int t = threadIdx.x, bid = blockIdx.x;
    // pass 1: scan global chunk partials (redundant per block, L2-hot 784 B)
    sm[t] = (t < NCH) ? part[t] : 0;
    __syncthreads();
    for (int off = 1; off < 256; off <<= 1) {
        int u = 0; if (t >= off) u = sm[t - off];
        __syncthreads(); sm[t] += u; __syncthreads();
    }
    const int base0 = (bid > 0) ? sm[bid - 1] : 0;
    __syncthreads();                      // protect sm before reuse
    // pass 2: intra-chunk exclusive positions
    int base = bid * 1024 + t * 4;
    int v[4]; int s = 0;
    #pragma unroll
    for (int i = 0; i < 4; ++i) { int idx = base + i; v[i] = (idx < EN) ? cnt[idx] : 0; s += v[i]; }
    sm[t] = s; __syncthreads();
    for (int off = 1; off < 256; off <<= 1) {
        int u = 0; if (t >= off) u = sm[t - off];
        __syncthreads(); sm[t] += u; __syncthreads();
    }
    int ex = ((t > 0) ? sm[t - 1] : 0) + base0;
    #pragma unroll
    for (int i = 0; i < 4; ++i) {
        int idx = base + i;
        if (idx < EN) { col_start[idx] = ex; ex += v[i]; ccur[idx] = 0; }
    }
    // block 0 extras: 16-padded relation bases + bk pad-init
    if (bid == 0) {
        if (t == 0) {
            int acc = 0;
            for (int r = 0; r < R; ++r) {
                sbase[r] = acc; rbase[r] = acc; cursor[r] = acc;
                int c0 = rcnt[r]; scnt[r] = c0;
                acc += (c0 + 15) & ~15;   // 16-aligned bucket regions
            }
            sbase[R] = acc; rbase[R] = acc;
            col_start[EN] = EN;
        }
        __syncthreads();
        // pads: row=0 (safe gather), dst=EN (dump row), coef=0 (no contribution)
        for (int r = 0; r < R; ++r) {
            int ps = sbase[r] + scnt[r], pe = sbase[r + 1];
            for (int i = ps + t; i < pe; i += 256)
                bk_pack[i] = make_int4(0, EN, 0, 0);
        }
    }
}

// ---------- bucket by relation (16-padded) + col-sorted slot + coef + crel ----------
__global__ void k_bucket(const int* __restrict__ row, const int* __restrict__ col,
                         const int* __restrict__ etype, const float* __restrict__ attr,
                         const float* __restrict__ dinv, const int* __restrict__ col_start,
                         int* __restrict__ cursor, int* __restrict__ ccur,
                         int4* __restrict__ bk_pack, float* __restrict__ crel) {
    __shared__ int lcnt[R];
    __shared__ int lbase[R];
    int t = threadIdx.x;
    if (t < R) lcnt[t] = 0;
    __syncthreads();
    int e = blockIdx.x * 256 + t;
    int r = 0, rank = 0, c = 0, rw = 0;
    float cf = 0.f;
    if (e < EN) {
        r = etype[e];
        rank = atomicAdd(&lcnt[r], 1);
        c = col[e]; rw = row[e];
        cf = attr[e] * dinv[rw] * dinv[c];
    }
    __syncthreads();
    if (t < R) lbase[t] = lcnt[t] ? atomicAdd(&cursor[t], lcnt[t]) : 0;
    __syncthreads();
    if (e < EN) {
        int pos = lbase[r] + rank;                       // padded relation bucket
        int sp = col_start[c] + atomicAdd(&ccur[c], 1);  // col-sorted slot
        bk_pack[pos] = make_int4(rw, sp, __float_as_int(cf), 0);
        atomicAdd(&crel[c * 4 + r], cf);
    }
}

// ================= MFMA GEMM: flat 1-D tile grid over padded buckets =================
// LAYER 2: B-frags = z1 on the fly from crel[srow] (16 B) vs LDS s1/b1; writes msg2.
// LAYER 3: B-frags = z2 on the fly from msg2 segment [col_start[srow],col_start[srow+1])
//          (col-sorted => contiguous; E[deg]=1) + b2 + leaky; writes msg3.
//          Same p-ascending fp32 sum as the old agg2 -> z2 bits identical.
template<int LAYER>
__global__ __launch_bounds__(256)
void k_gemm(const unsigned short* __restrict__ msrc,    // LAYER 3: msg2
            const unsigned short* __restrict__ wsw,
            const int4* __restrict__ bk_pack, const int* __restrict__ rbase,
            const int* __restrict__ col_start,
            const float* __restrict__ crel, const float* __restrict__ s1g,
            const float* __restrict__ b1, const float* __restrict__ b2,
            unsigned short* __restrict__ mdst) {
    const int t = threadIdx.x;
    __shared__ unsigned short xpose[4][16 * 144];   // 18 KB; wave-private regions
    __shared__ float ls1[R * D];
    __shared__ float lb[D];                         // b1 (L2) or b2 (L3)
    if constexpr (LAYER == 2) {
        ls1[t] = s1g[t];
        ls1[t + 256] = s1g[t + 256];
        if (t < D) lb[t] = b1[t];
    } else {
        if (t < D) lb[t] = b2[t];
    }
    __syncthreads();                        // before any wave can early-exit
    const int tile = blockIdx.x * 4 + (t >> 6);
    const int e16 = tile * 16;
    if (e16 >= rbase[R]) return;            // wave-uniform early exit (tail only)
    const int r = (e16 >= rbase[1]) + (e16 >= rbase[2]) + (e16 >= rbase[3]);
    const int l = t & 63, q = l >> 4, n16 = l & 15;
    const int p = e16 + n16;                // always in-bounds (padded buckets)
    const int4 bk = bk_pack[p];             // one 16 B load: {row, dst, coef, -}
    const int srow = bk.x;
    const int dp = bk.y;
    const float cf = __int_as_float(bk.z);

    // B-frags: x[edge][k]; lane covers k = s*32 + q*8 .. +8
    bf16x8 xf[4];
    if constexpr (LAYER == 2) {
        const float4 cr = ((const float4*)crel)[srow];   // 16 B instead of 256 B row
        #pragma unroll
        for (int s = 0; s < 4; ++s) {
            union { unsigned short us[8]; bf16x8 v; } o;
            #pragma unroll
            for (int j = 0; j < 8; ++j) {
                int k = s * 32 + q * 8 + j;
                float xv = lb[k] + cr.x * ls1[k] + cr.y * ls1[D + k]
                         + cr.z * ls1[2 * D + k] + cr.w * ls1[3 * D + k];
                xv = (xv > 0.f) ? xv : NEG * xv;
                o.us[j] = f2bf(xv);
            }
            xf[s] = o.v;
        }
    } else {
        // z2 on the fly: fp32 segment sum over msg2 (pads: srow=0, harmless)
        const int st = col_start[srow], en = col_start[srow + 1];
        float za[32];
        #pragma unroll
        for (int i = 0; i < 32; ++i) za[i] = 0.f;
        for (int p2 = st; p2 < en; ++p2) {
            const unsigned short* mrow = msrc + (size_t)p2 * D + q * 8;
            #pragma unroll
            for (int s = 0; s < 4; ++s) {
                uint4 u = *(const uint4*)(mrow + s * 32);
                za[s * 8 + 0] += bflo(u.x); za[s * 8 + 1] += bfhi(u.x);
                za[s * 8 + 2] += bflo(u.y); za[s * 8 + 3] += bfhi(u.y);
                za[s * 8 + 4] += bflo(u.z); za[s * 8 + 5] += bfhi(u.z);
                za[s * 8 + 6] += bflo(u.w); za[s * 8 + 7] += bfhi(u.w);
            }
        }
        #pragma unroll
        for (int s = 0; s < 4; ++s) {
            union { unsigned short us[8]; bf16x8 v; } o;
            #pragma unroll
            for (int j = 0; j < 8; ++j) {
                float xv = za[s * 8 + j] + lb[s * 32 + q * 8 + j];
                xv = (xv > 0.f) ? xv : NEG * xv;
                o.us[j] = f2bf(xv);
            }
            xf[s] = o.v;
        }
    }

    // A-frags: swizzled W, L1/L2-resident
    const unsigned short* wr = wsw + ((size_t)r * 2048 + l) * 8;

    f32x4 acc[8];
    #pragma unroll
    for (int mt = 0; mt < 8; ++mt) acc[mt] = (f32x4){0.f, 0.f, 0.f, 0.f};

    #pragma unroll
    for (int s = 0; s < 4; ++s) {
        #pragma unroll
        for (int mt = 0; mt < 8; ++mt) {
            bf16x8 wf = *(const bf16x8*)(wr + (size_t)(s * 512 + mt * 64) * 8);
            acc[mt] = __builtin_amdgcn_mfma_f32_16x16x32_bf16(wf, xf[s], acc[mt], 0, 0, 0);
        }
    }

    // epilogue: scale, pack, transpose through wave-private LDS, coalesced store
    unsigned short* lbuf = xpose[t >> 6];
    #pragma unroll
    for (int mt = 0; mt < 8; ++mt) {
        uint2 u;
        u.x = pack2bf(acc[mt].x * cf, acc[mt].y * cf);
        u.y = pack2bf(acc[mt].z * cf, acc[mt].w * cf);
        *(uint2*)&lbuf[n16 * 144 + mt * 16 + q * 4] = u;
    }
    #pragma unroll
    for (int ro = 0; ro < 4; ++ro) {
        int e = ro * 4 + q;
        uint4 v = *(const uint4*)&lbuf[e * 144 + n16 * 8];
        int rdp = __shfl(dp, e);
        *(uint4*)(mdst + (size_t)rdp * D + n16 * 8) = v;
    }
}

// ================= final combine: one pass over msg2+msg3 (same segments) =================
// dout = (1 + z1(crel) + z2(msg2) + z3(msg3)) * 0.25; z1,z2 fp32 (never materialized)
__global__ void k_agg3(const unsigned* __restrict__ m2, const unsigned* __restrict__ m3,
                       const float* __restrict__ b2v, const float* __restrict__ b3v,
                       const int* __restrict__ col_start,
                       const float* __restrict__ crel, const float* __restrict__ s1g,
                       const float* __restrict__ b1, float* __restrict__ dout) {
    __shared__ float ls1[R * D];
    __shared__ float lb1[D], lb2[D], lb3[D];
    int t = threadIdx.x;
    ls1[t] = s1g[t];
    ls1[t + 256] = s1g[t + 256];
    if (t < D) { lb1[t] = b1[t]; lb2[t] = b2v[t]; lb3[t] = b3v[t]; }
    __syncthreads();
    int lane = t & 63;
    for (int c = blockIdx.x * 4 + (t >> 6); c < EN; c += gridDim.x * 4) {
        int st = col_start[c], pe = col_start[c + 1];
        float s20 = 0.f, s21 = 0.f, s30 = 0.f, s31 = 0.f;
        for (int p = st; p < pe; ++p) {
            unsigned u2 = m2[(size_t)p * 64 + lane];
            unsigned u3 = m3[(size_t)p * 64 + lane];
            s20 += bflo(u2); s21 += bfhi(u2);
            s30 += bflo(u3); s31 += bfhi(u3);
        }
        int d0 = lane * 2, d1 = d0 + 1;
        float z2a = s20 + lb2[d0], z2b = s21 + lb2[d1];
        z2a = (z2a > 0.f) ? z2a : NEG * z2a;
        z2b = (z2b > 0.f) ? z2b : NEG * z2b;
        float z3a = s30 + lb3[d0], z3b = s31 + lb3[d1];
        z3a = (z3a > 0.f) ? z3a : NEG * z3a;
        z3b = (z3b > 0.f) ? z3b : NEG * z3b;
        float4 cr = ((const float4*)crel)[c];   // wave-uniform 16 B
        float z1a = lb1[d0] + cr.x * ls1[d0] + cr.y * ls1[D + d0]
                  + cr.z * ls1[2 * D + d0] + cr.w * ls1[3 * D + d0];
        float z1b = lb1[d1] + cr.x * ls1[d1] + cr.y * ls1[D + d1]
                  + cr.z * ls1[2 * D + d1] + cr.w * ls1[3 * D + d1];
        z1a = (z1a > 0.f) ? z1a : NEG * z1a;
        z1b = (z1b > 0.f) ? z1b : NEG * z1b;
        float2 o;
        o.x = (1.f + z1a + z2a + z3a) * 0.25f;
        o.y = (1.f + z1b + z2b + z3b) * 0.25f;
        ((float2*)(dout + (size_t)c * D))[lane] = o;
    }
}

extern "C" void kernel_launch(void* const* d_in, const int* in_sizes, int n_in,
                              void* d_out, int out_size, void* d_ws, size_t ws_size,
                              hipStream_t stream) {
    const int*   eidx = (const int*)d_in[0];     // [2, E]
    const int*   row  = eidx;
    const int*   col  = eidx + EN;
    const int*   etyp = (const int*)d_in[1];
    const float* attr = (const float*)d_in[2];
    const float* w1   = (const float*)d_in[3];
    const float* b1   = (const float*)d_in[4];
    const float* w2   = (const float*)d_in[5];
    const float* b2   = (const float*)d_in[6];
    const float* w3   = (const float*)d_in[7];
    const float* b3   = (const float*)d_in[8];
    float* dout = (float*)d_out;

    // workspace layout (~115 MB; ws is ~409.6 MB per harness poison size)
    char* wsb = (char*)d_ws;
    size_t off = 0;
    unsigned short* msg2 = (unsigned short*)(wsb + off); off += (size_t)(EN + 1) * D * 2 + 512;
    unsigned short* msg3 = (unsigned short*)(wsb + off); off += (size_t)(EN + 1) * D * 2 + 512;
    int*   col_start = (int*)(wsb + off); off += 800032;
    int*   cnt       = (int*)(wsb + off); off += (size_t)EN * 4;
    int*   rcnt      = (int*)(wsb + off); off += 16;          // contiguous after cnt
    float* crel      = (float*)(wsb + off); off += (size_t)EN * 16;  // contiguous after rcnt
    int4*  bk_pack   = (int4*)(wsb + off); off += (size_t)(EN + 64) * 16;
    float* dinv      = (float*)(wsb + off); off += (size_t)EN * 4;
    unsigned short* w2b = (unsigned short*)(wsb + off); off += 131072;
    unsigned short* w3b = (unsigned short*)(wsb + off); off += 131072;
    int*   part      = (int*)(wsb + off); off += 1024;
    int*   rbase     = (int*)(wsb + off); off += 32;
    int*   cursor    = (int*)(wsb + off); off += 16;
    float* s1        = (float*)(wsb + off); off += (size_t)R * D * 4;
    int*   ccur      = (int*)msg2;   // aliased: msg2 not live until GEMM layer 2

    dim3 blk(256);

    // zero cnt + rcnt + crel in one contiguous memset
    hipMemsetAsync(cnt, 0, (size_t)EN * 4 + 16 + (size_t)EN * 16, stream);
    // histogram + W prep
    k_cntprep<<<NBLKE + NPREP, blk, 0, stream>>>(col, etyp, w1, w2, w3,
                                                 cnt, rcnt, w2b, w3b, s1);
    // scans: chunk sums + dinv, then fused rescan + col_start + ccur + block0 extras
    k_scanA<<<NCH, blk, 0, stream>>>(cnt, part, dinv);
    k_scanB<<<NCH, blk, 0, stream>>>(cnt, part, rcnt, rbase, cursor, col_start,
                                     ccur, bk_pack);
    // bucket + col-sort placement + coef + crel accumulation
    k_bucket<<<NBLKE, blk, 0, stream>>>(row, col, etyp, attr, dinv, col_start,
                                        cursor, ccur, bk_pack, crel);

    // layers 2,3: flat-tile GEMM (z1, z2 both on the fly) + single final combine
    const int nTiles = ceil_div(EN + 64, 16);
    const int gB = ceil_div(nTiles, 4);              // 3126 blocks
    k_gemm<2><<<gB, blk, 0, stream>>>(nullptr, w2b, bk_pack, rbase, col_start,
                                      crel, s1, b1, b2, msg2);
    k_gemm<3><<<gB, blk, 0, stream>>>(msg2, w3b, bk_pack, rbase, col_start,
                                      crel, s1, b1, b2, msg3);
    k_agg3<<<2048, blk, 0, stream>>>((const unsigned*)msg2, (const unsigned*)msg3,
                                     b2, b3, col_start, crel, s1, b1, dout);
}

// Round 12
// 257.361 us; speedup vs baseline: 1.1181x; 1.0309x over previous
//
#include <hip/hip_runtime.h>
#include <math.h>

// Problem constants (match reference)
constexpr int EN = 200000;   // edges == nodes
constexpr int D  = 128;      // embedding dim
constexpr int R  = 4;        // relation types
constexpr float NEG = 0.01f;

constexpr int NBLKE = (EN + 255) / 256;   // 782 histogram blocks
constexpr int NPREP = 66;                 // 16896 prep threads
constexpr int NCH   = (EN + 1023) / 1024; // 196 scan chunks (must be <= 256)

static inline int ceil_div(int a, int b) { return (a + b - 1) / b; }

typedef __attribute__((ext_vector_type(8))) __bf16 bf16x8;
typedef __attribute__((ext_vector_type(4))) float f32x4;

// ---------- bf16 helpers (RNE) ----------
__device__ __forceinline__ unsigned short f2bf(float f) {
    union { float f; unsigned u; } v; v.f = f;
    unsigned u = v.u + 0x7fffu + ((v.u >> 16) & 1u);
    return (unsigned short)(u >> 16);
}
__device__ __forceinline__ unsigned pack2bf(float a, float b) {
    return (unsigned)f2bf(a) | ((unsigned)f2bf(b) << 16);
}
__device__ __forceinline__ float bflo(unsigned m) { return __uint_as_float(m << 16); }
__device__ __forceinline__ float bfhi(unsigned m) { return __uint_as_float(m & 0xffff0000u); }

// ---------- W pre-swizzle to MFMA A-frag bf16 ----------
__device__ __forceinline__ void wswz_one(const float* __restrict__ w,
                                         unsigned short* __restrict__ wsw, int t) {
    int lane = t & 63, mt = (t >> 6) & 7, s = (t >> 9) & 3, r = t >> 11;
    int q = lane >> 4, n = mt * 16 + (lane & 15);
    union { unsigned short us[8]; uint4 u4; } o;
    #pragma unroll
    for (int j = 0; j < 8; ++j) {
        int k = s * 32 + q * 8 + j;
        o.us[j] = f2bf(w[((size_t)r * D + k) * D + n]);
    }
    *(uint4*)(wsw + (size_t)t * 8) = o.u4;
}

// ---------- histogram (col degree + relation counts) + W prep, one dispatch ----------
__global__ void k_cntprep(const int* __restrict__ col, const int* __restrict__ etyp,
                          const float* __restrict__ w1, const float* __restrict__ w2,
                          const float* __restrict__ w3,
                          int* __restrict__ cnt, int* __restrict__ rcnt,
                          unsigned short* __restrict__ w2b, unsigned short* __restrict__ w3b,
                          float* __restrict__ s1) {
    const int b = blockIdx.x, t = threadIdx.x;
    if (b < NBLKE) {
        __shared__ int lr[R];
        if (t < R) lr[t] = 0;
        __syncthreads();
        int e = b * 256 + t;
        if (e < EN) {
            atomicAdd(&cnt[col[e]], 1);
            atomicAdd(&lr[etyp[e]], 1);
        }
        __syncthreads();
        if (t < R && lr[t]) atomicAdd(&rcnt[t], lr[t]);
    } else {
        int g = (b - NBLKE) * 256 + t;     // 0..16895
        if (g < 8192) {
            wswz_one(w2, w2b, g);
        } else if (g < 16384) {
            wswz_one(w3, w3b, g - 8192);
        } else if (g < 16896) {
            int t2 = g - 16384;            // 0..511: colsum(W1)
            int r = t2 >> 7, j = t2 & (D - 1);
            float s = 0.f;
            for (int k = 0; k < D; ++k) s += w1[((r << 7) + k) * D + j];
            s1[t2] = s;
        }
    }
}

// ---------- scan A: per-1024-chunk sums + crel zeroing (consumer: bucket, 2 later) ----------
__global__ void k_scanA(const int* __restrict__ cnt, int* __restrict__ part,
                        float* __restrict__ crel) {
    __shared__ int sm[256];
    int t = threadIdx.x;
    // zero crel: 200000 int4, ~4 per thread, spread across the grid
    {
        int4* cz = (int4*)crel;
        int4 z = make_int4(0, 0, 0, 0);
        for (int i = blockIdx.x * 256 + t; i < EN; i += NCH * 256) cz[i] = z;
    }
    int base = blockIdx.x * 1024 + t * 4;
    int s = 0;
    #pragma unroll
    for (int i = 0; i < 4; ++i) { int idx = base + i; if (idx < EN) s += cnt[idx]; }
    sm[t] = s; __syncthreads();
    for (int off = 128; off > 0; off >>= 1) {
        if (t < off) sm[t] += sm[t + off];
        __syncthreads();
    }
    if (t == 0) part[blockIdx.x] = sm[0];
}

// ---------- scan B: redundant global rescan + col_start + ccur, block0 extras ----------
__global__ void k_scanB(const int* __restrict__ cnt, const int* __restrict__ part,
                        const int* __restrict__ rcnt,
                        int* __restrict__ rbase, int* __restrict__ cursor,
                        int* __restrict__ col_start, int* __restrict__ ccur,
                        int4* __restrict__ bk_pack) {
    __shared__ int sm[256];
    __shared__ int sbase[R + 1];
    __shared__ int scnt[R];
    int t = threadIdx.x, bid = blockIdx.x;
    // pass 1: scan global chunk partials (redundant per block, L2-hot 784 B)
    sm[t] = (t < NCH) ? part[t] : 0;
    __syncthreads();
    for (int off = 1; off < 256; off <<= 1) {
        int u = 0; if (t >= off) u = sm[t - off];
        __syncthreads(); sm[t] += u; __syncthreads();
    }
    const int base0 = (bid > 0) ? sm[bid - 1] : 0;
    __syncthreads();                      // protect sm before reuse
    // pass 2: intra-chunk exclusive positions
    int base = bid * 1024 + t * 4;
    int v[4]; int s = 0;
    #pragma unroll
    for (int i = 0; i < 4; ++i) { int idx = base + i; v[i] = (idx < EN) ? cnt[idx] : 0; s += v[i]; }
    sm[t] = s; __syncthreads();
    for (int off = 1; off < 256; off <<= 1) {
        int u = 0; if (t >= off) u = sm[t - off];
        __syncthreads(); sm[t] += u; __syncthreads();
    }
    int ex = ((t > 0) ? sm[t - 1] : 0) + base0;
    #pragma unroll
    for (int i = 0; i < 4; ++i) {
        int idx = base + i;
        if (idx < EN) { col_start[idx] = ex; ex += v[i]; ccur[idx] = 0; }
    }
    // block 0 extras: 16-padded relation bases + bk pad-init
    if (bid == 0) {
        if (t == 0) {
            int acc = 0;
            for (int r = 0; r < R; ++r) {
                sbase[r] = acc; rbase[r] = acc; cursor[r] = acc;
                int c0 = rcnt[r]; scnt[r] = c0;
                acc += (c0 + 15) & ~15;   // 16-aligned bucket regions
            }
            sbase[R] = acc; rbase[R] = acc;
            col_start[EN] = EN;
        }
        __syncthreads();
        // pads: row=0 (safe gather), dst=EN (dump row), coef=0 (no contribution)
        for (int r = 0; r < R; ++r) {
            int ps = sbase[r] + scnt[r], pe = sbase[r + 1];
            for (int i = ps + t; i < pe; i += 256)
                bk_pack[i] = make_int4(0, EN, 0, 0);
        }
    }
}

// ---------- bucket by relation (16-padded) + col-sorted slot + coef + crel ----------
// rsqrt computed inline from cnt (L2-hot) -- no dinv buffer.
__global__ void k_bucket(const int* __restrict__ row, const int* __restrict__ col,
                         const int* __restrict__ etype, const float* __restrict__ attr,
                         const int* __restrict__ cnt, const int* __restrict__ col_start,
                         int* __restrict__ cursor, int* __restrict__ ccur,
                         int4* __restrict__ bk_pack, float* __restrict__ crel) {
    __shared__ int lcnt[R];
    __shared__ int lbase[R];
    int t = threadIdx.x;
    if (t < R) lcnt[t] = 0;
    __syncthreads();
    int e = blockIdx.x * 256 + t;
    int r = 0, rank = 0, c = 0, rw = 0;
    float cf = 0.f;
    if (e < EN) {
        r = etype[e];
        rank = atomicAdd(&lcnt[r], 1);
        c = col[e]; rw = row[e];
        int dr = cnt[rw], dc = cnt[c];
        float a = (dr > 0) ? rsqrtf((float)dr) : 0.f;
        float b = (dc > 0) ? rsqrtf((float)dc) : 0.f;
        cf = attr[e] * a * b;
    }
    __syncthreads();
    if (t < R) lbase[t] = lcnt[t] ? atomicAdd(&cursor[t], lcnt[t]) : 0;
    __syncthreads();
    if (e < EN) {
        int pos = lbase[r] + rank;                       // padded relation bucket
        int sp = col_start[c] + atomicAdd(&ccur[c], 1);  // col-sorted slot
        bk_pack[pos] = make_int4(rw, sp, __float_as_int(cf), 0);
        atomicAdd(&crel[c * 4 + r], cf);
    }
}

// ================= MFMA GEMM: flat 1-D tile grid over padded buckets =================
// LAYER 2: B-frags = z1 on the fly from crel[srow] (16 B) vs LDS s1/b1; writes msg2.
// LAYER 3: B-frags = z2 on the fly from msg2 segment [col_start[srow],col_start[srow+1])
//          (col-sorted => contiguous; E[deg]=1) + b2 + leaky; writes msg3.
template<int LAYER>
__global__ __launch_bounds__(256)
void k_gemm(const unsigned short* __restrict__ msrc,    // LAYER 3: msg2
            const unsigned short* __restrict__ wsw,
            const int4* __restrict__ bk_pack, const int* __restrict__ rbase,
            const int* __restrict__ col_start,
            const float* __restrict__ crel, const float* __restrict__ s1g,
            const float* __restrict__ b1, const float* __restrict__ b2,
            unsigned short* __restrict__ mdst) {
    const int t = threadIdx.x;
    __shared__ unsigned short xpose[4][16 * 144];   // 18 KB; wave-private regions
    __shared__ float ls1[R * D];
    __shared__ float lb[D];                         // b1 (L2) or b2 (L3)
    if constexpr (LAYER == 2) {
        ls1[t] = s1g[t];
        ls1[t + 256] = s1g[t + 256];
        if (t < D) lb[t] = b1[t];
    } else {
        if (t < D) lb[t] = b2[t];
    }
    __syncthreads();                        // before any wave can early-exit
    const int tile = blockIdx.x * 4 + (t >> 6);
    const int e16 = tile * 16;
    if (e16 >= rbase[R]) return;            // wave-uniform early exit (tail only)
    const int r = (e16 >= rbase[1]) + (e16 >= rbase[2]) + (e16 >= rbase[3]);
    const int l = t & 63, q = l >> 4, n16 = l & 15;
    const int p = e16 + n16;                // always in-bounds (padded buckets)
    const int4 bk = bk_pack[p];             // one 16 B load: {row, dst, coef, -}
    const int srow = bk.x;
    const int dp = bk.y;
    const float cf = __int_as_float(bk.z);

    // B-frags: x[edge][k]; lane covers k = s*32 + q*8 .. +8
    bf16x8 xf[4];
    if constexpr (LAYER == 2) {
        const float4 cr = ((const float4*)crel)[srow];   // 16 B instead of 256 B row
        #pragma unroll
        for (int s = 0; s < 4; ++s) {
            union { unsigned short us[8]; bf16x8 v; } o;
            #pragma unroll
            for (int j = 0; j < 8; ++j) {
                int k = s * 32 + q * 8 + j;
                float xv = lb[k] + cr.x * ls1[k] + cr.y * ls1[D + k]
                         + cr.z * ls1[2 * D + k] + cr.w * ls1[3 * D + k];
                xv = (xv > 0.f) ? xv : NEG * xv;
                o.us[j] = f2bf(xv);
            }
            xf[s] = o.v;
        }
    } else {
        // z2 on the fly: fp32 segment sum over msg2 (pads: srow=0, harmless)
        const int st = col_start[srow], en = col_start[srow + 1];
        float za[32];
        #pragma unroll
        for (int i = 0; i < 32; ++i) za[i] = 0.f;
        for (int p2 = st; p2 < en; ++p2) {
            const unsigned short* mrow = msrc + (size_t)p2 * D + q * 8;
            #pragma unroll
            for (int s = 0; s < 4; ++s) {
                uint4 u = *(const uint4*)(mrow + s * 32);
                za[s * 8 + 0] += bflo(u.x); za[s * 8 + 1] += bfhi(u.x);
                za[s * 8 + 2] += bflo(u.y); za[s * 8 + 3] += bfhi(u.y);
                za[s * 8 + 4] += bflo(u.z); za[s * 8 + 5] += bfhi(u.z);
                za[s * 8 + 6] += bflo(u.w); za[s * 8 + 7] += bfhi(u.w);
            }
        }
        #pragma unroll
        for (int s = 0; s < 4; ++s) {
            union { unsigned short us[8]; bf16x8 v; } o;
            #pragma unroll
            for (int j = 0; j < 8; ++j) {
                float xv = za[s * 8 + j] + lb[s * 32 + q * 8 + j];
                xv = (xv > 0.f) ? xv : NEG * xv;
                o.us[j] = f2bf(xv);
            }
            xf[s] = o.v;
        }
    }

    // A-frags: swizzled W, L1/L2-resident
    const unsigned short* wr = wsw + ((size_t)r * 2048 + l) * 8;

    f32x4 acc[8];
    #pragma unroll
    for (int mt = 0; mt < 8; ++mt) acc[mt] = (f32x4){0.f, 0.f, 0.f, 0.f};

    #pragma unroll
    for (int s = 0; s < 4; ++s) {
        #pragma unroll
        for (int mt = 0; mt < 8; ++mt) {
            bf16x8 wf = *(const bf16x8*)(wr + (size_t)(s * 512 + mt * 64) * 8);
            acc[mt] = __builtin_amdgcn_mfma_f32_16x16x32_bf16(wf, xf[s], acc[mt], 0, 0, 0);
        }
    }

    // epilogue: scale, pack, transpose through wave-private LDS, coalesced store
    unsigned short* lbuf = xpose[t >> 6];
    #pragma unroll
    for (int mt = 0; mt < 8; ++mt) {
        uint2 u;
        u.x = pack2bf(acc[mt].x * cf, acc[mt].y * cf);
        u.y = pack2bf(acc[mt].z * cf, acc[mt].w * cf);
        *(uint2*)&lbuf[n16 * 144 + mt * 16 + q * 4] = u;
    }
    #pragma unroll
    for (int ro = 0; ro < 4; ++ro) {
        int e = ro * 4 + q;
        uint4 v = *(const uint4*)&lbuf[e * 144 + n16 * 8];
        int rdp = __shfl(dp, e);
        *(uint4*)(mdst + (size_t)rdp * D + n16 * 8) = v;
    }
}

// ================= final combine: 2 columns/wave, uint2 loads =================
// dout = (1 + z1(crel) + z2(msg2) + z3(msg3)) * 0.25; z1,z2 fp32 (never materialized).
// Half-wave h handles one column: lane32 covers dims 4*l32..4*l32+3 (uint2 = 8 B/lane).
// Per-dimension fp32 sum order (ascending p) unchanged -> bit-identical output.
__global__ void k_agg3(const unsigned* __restrict__ m2, const unsigned* __restrict__ m3,
                       const float* __restrict__ b2v, const float* __restrict__ b3v,
                       const int* __restrict__ col_start,
                       const float* __restrict__ crel, const float* __restrict__ s1g,
                       const float* __restrict__ b1, float* __restrict__ dout) {
    __shared__ float ls1[R * D];
    __shared__ float lb1[D], lb2[D], lb3[D];
    int t = threadIdx.x;
    ls1[t] = s1g[t];
    ls1[t + 256] = s1g[t + 256];
    if (t < D) { lb1[t] = b1[t]; lb2[t] = b2v[t]; lb3[t] = b3v[t]; }
    __syncthreads();
    const int h = t >> 5, l32 = t & 31;     // 8 half-waves -> 8 columns per block
    const uint2* m2v = (const uint2*)m2;
    const uint2* m3v = (const uint2*)m3;
    for (int c = blockIdx.x * 8 + h; c < EN; c += gridDim.x * 8) {
        int st = col_start[c], pe = col_start[c + 1];
        float s2[4] = {0.f, 0.f, 0.f, 0.f};
        float s3[4] = {0.f, 0.f, 0.f, 0.f};
        for (int p = st; p < pe; ++p) {
            uint2 u2 = m2v[(size_t)p * 32 + l32];
            uint2 u3 = m3v[(size_t)p * 32 + l32];
            s2[0] += bflo(u2.x); s2[1] += bfhi(u2.x);
            s2[2] += bflo(u2.y); s2[3] += bfhi(u2.y);
            s3[0] += bflo(u3.x); s3[1] += bfhi(u3.x);
            s3[2] += bflo(u3.y); s3[3] += bfhi(u3.y);
        }
        float4 cr = ((const float4*)crel)[c];   // uniform within half-wave
        int d0 = l32 * 4;
        float o[4];
        #pragma unroll
        for (int j = 0; j < 4; ++j) {
            int d = d0 + j;
            float z2 = s2[j] + lb2[d];
            z2 = (z2 > 0.f) ? z2 : NEG * z2;
            float z3 = s3[j] + lb3[d];
            z3 = (z3 > 0.f) ? z3 : NEG * z3;
            float z1 = lb1[d] + cr.x * ls1[d] + cr.y * ls1[D + d]
                     + cr.z * ls1[2 * D + d] + cr.w * ls1[3 * D + d];
            z1 = (z1 > 0.f) ? z1 : NEG * z1;
            o[j] = (1.f + z1 + z2 + z3) * 0.25f;
        }
        float4 ov = make_float4(o[0], o[1], o[2], o[3]);
        ((float4*)(dout + (size_t)c * D))[l32] = ov;
    }
}

extern "C" void kernel_launch(void* const* d_in, const int* in_sizes, int n_in,
                              void* d_out, int out_size, void* d_ws, size_t ws_size,
                              hipStream_t stream) {
    const int*   eidx = (const int*)d_in[0];     // [2, E]
    const int*   row  = eidx;
    const int*   col  = eidx + EN;
    const int*   etyp = (const int*)d_in[1];
    const float* attr = (const float*)d_in[2];
    const float* w1   = (const float*)d_in[3];
    const float* b1   = (const float*)d_in[4];
    const float* w2   = (const float*)d_in[5];
    const float* b2   = (const float*)d_in[6];
    const float* w3   = (const float*)d_in[7];
    const float* b3   = (const float*)d_in[8];
    float* dout = (float*)d_out;

    // workspace layout (~114 MB; ws is ~409.6 MB per harness poison size)
    char* wsb = (char*)d_ws;
    size_t off = 0;
    unsigned short* msg2 = (unsigned short*)(wsb + off); off += (size_t)(EN + 1) * D * 2 + 512;
    unsigned short* msg3 = (unsigned short*)(wsb + off); off += (size_t)(EN + 1) * D * 2 + 512;
    int*   col_start = (int*)(wsb + off); off += 800032;
    int*   cnt       = (int*)(wsb + off); off += (size_t)EN * 4;
    int*   rcnt      = (int*)(wsb + off); off += 16;          // contiguous after cnt
    float* crel      = (float*)(wsb + off); off += (size_t)EN * 16;
    int4*  bk_pack   = (int4*)(wsb + off); off += (size_t)(EN + 64) * 16;
    unsigned short* w2b = (unsigned short*)(wsb + off); off += 131072;
    unsigned short* w3b = (unsigned short*)(wsb + off); off += 131072;
    int*   part      = (int*)(wsb + off); off += 1024;
    int*   rbase     = (int*)(wsb + off); off += 32;
    int*   cursor    = (int*)(wsb + off); off += 16;
    float* s1        = (float*)(wsb + off); off += (size_t)R * D * 4;
    int*   ccur      = (int*)msg2;   // aliased: msg2 not live until GEMM layer 2

    dim3 blk(256);

    // zero cnt + rcnt only (0.8 MB); crel zeroed inside k_scanA
    hipMemsetAsync(cnt, 0, (size_t)EN * 4 + 16, stream);
    // histogram + W prep
    k_cntprep<<<NBLKE + NPREP, blk, 0, stream>>>(col, etyp, w1, w2, w3,
                                                 cnt, rcnt, w2b, w3b, s1);
    // scans: chunk sums + crel zero, then fused rescan + col_start + ccur + extras
    k_scanA<<<NCH, blk, 0, stream>>>(cnt, part, crel);
    k_scanB<<<NCH, blk, 0, stream>>>(cnt, part, rcnt, rbase, cursor, col_start,
                                     ccur, bk_pack);
    // bucket + col-sort placement + coef (rsqrt inline from cnt) + crel accumulation
    k_bucket<<<NBLKE, blk, 0, stream>>>(row, col, etyp, attr, cnt, col_start,
                                        cursor, ccur, bk_pack, crel);

    // layers 2,3: flat-tile GEMM (z1, z2 both on the fly) + single final combine
    const int nTiles = ceil_div(EN + 64, 16);
    const int gB = ceil_div(nTiles, 4);              // 3126 blocks
    k_gemm<2><<<gB, blk, 0, stream>>>(nullptr, w2b, bk_pack, rbase, col_start,
                                      crel, s1, b1, b2, msg2);
    k_gemm<3><<<gB, blk, 0, stream>>>(msg2, w3b, bk_pack, rbase, col_start,
                                      crel, s1, b1, b2, msg3);
    k_agg3<<<2048, blk, 0, stream>>>((const unsigned*)msg2, (const unsigned*)msg3,
                                     b2, b3, col_start, crel, s1, b1, dout);
}

// Round 13
// 248.162 us; speedup vs baseline: 1.1596x; 1.0371x over previous
//
#include <hip/hip_runtime.h>
#include <math.h>

// Problem constants (match reference)
constexpr int EN = 200000;   // edges == nodes
constexpr int D  = 128;      // embedding dim
constexpr int R  = 4;        // relation types
constexpr float NEG = 0.01f;

constexpr int NBLKE4 = (EN + 1023) / 1024; // 196 edge blocks (4 edges/thread)
constexpr int NPREP  = 66;                 // 16896 prep threads
constexpr int NCH    = (EN + 1023) / 1024; // 196 scan chunks (must be <= 256)

static inline int ceil_div(int a, int b) { return (a + b - 1) / b; }

typedef __attribute__((ext_vector_type(8))) __bf16 bf16x8;
typedef __attribute__((ext_vector_type(4))) float f32x4;

// ---------- bf16 helpers (RNE) ----------
__device__ __forceinline__ unsigned short f2bf(float f) {
    union { float f; unsigned u; } v; v.f = f;
    unsigned u = v.u + 0x7fffu + ((v.u >> 16) & 1u);
    return (unsigned short)(u >> 16);
}
__device__ __forceinline__ unsigned pack2bf(float a, float b) {
    return (unsigned)f2bf(a) | ((unsigned)f2bf(b) << 16);
}
__device__ __forceinline__ float bflo(unsigned m) { return __uint_as_float(m << 16); }
__device__ __forceinline__ float bfhi(unsigned m) { return __uint_as_float(m & 0xffff0000u); }

// ---------- W pre-swizzle to MFMA A-frag bf16 ----------
__device__ __forceinline__ void wswz_one(const float* __restrict__ w,
                                         unsigned short* __restrict__ wsw, int t) {
    int lane = t & 63, mt = (t >> 6) & 7, s = (t >> 9) & 3, r = t >> 11;
    int q = lane >> 4, n = mt * 16 + (lane & 15);
    union { unsigned short us[8]; uint4 u4; } o;
    #pragma unroll
    for (int j = 0; j < 8; ++j) {
        int k = s * 32 + q * 8 + j;
        o.us[j] = f2bf(w[((size_t)r * D + k) * D + n]);
    }
    *(uint4*)(wsw + (size_t)t * 8) = o.u4;
}

// ---------- histogram (4 edges/thread, int4 loads) + W prep, one dispatch ----------
__global__ void k_cntprep(const int* __restrict__ col, const int* __restrict__ etyp,
                          const float* __restrict__ w1, const float* __restrict__ w2,
                          const float* __restrict__ w3,
                          int* __restrict__ cnt, int* __restrict__ rcnt,
                          unsigned short* __restrict__ w2b, unsigned short* __restrict__ w3b,
                          float* __restrict__ s1) {
    const int b = blockIdx.x, t = threadIdx.x;
    if (b < NBLKE4) {
        __shared__ int lr[R];
        if (t < R) lr[t] = 0;
        __syncthreads();
        int e0 = b * 1024 + t * 4;
        if (e0 + 3 < EN) {
            int4 c4 = *(const int4*)(col + e0);
            int4 y4 = *(const int4*)(etyp + e0);
            atomicAdd(&cnt[c4.x], 1); atomicAdd(&cnt[c4.y], 1);
            atomicAdd(&cnt[c4.z], 1); atomicAdd(&cnt[c4.w], 1);
            atomicAdd(&lr[y4.x], 1); atomicAdd(&lr[y4.y], 1);
            atomicAdd(&lr[y4.z], 1); atomicAdd(&lr[y4.w], 1);
        } else {
            for (int e = e0; e < EN; ++e) {
                atomicAdd(&cnt[col[e]], 1);
                atomicAdd(&lr[etyp[e]], 1);
            }
        }
        __syncthreads();
        if (t < R && lr[t]) atomicAdd(&rcnt[t], lr[t]);
    } else {
        int g = (b - NBLKE4) * 256 + t;    // 0..16895
        if (g < 8192) {
            wswz_one(w2, w2b, g);
        } else if (g < 16384) {
            wswz_one(w3, w3b, g - 8192);
        } else if (g < 16896) {
            int t2 = g - 16384;            // 0..511: colsum(W1)
            int r = t2 >> 7, j = t2 & (D - 1);
            float s = 0.f;
            for (int k = 0; k < D; ++k) s += w1[((r << 7) + k) * D + j];
            s1[t2] = s;
        }
    }
}

// ---------- scan A: per-1024-chunk sums + crel zeroing (consumer: bucket, 2 later) ----------
__global__ void k_scanA(const int* __restrict__ cnt, int* __restrict__ part,
                        float* __restrict__ crel) {
    __shared__ int sm[256];
    int t = threadIdx.x;
    // zero crel: 200000 int4, ~4 per thread, spread across the grid
    {
        int4* cz = (int4*)crel;
        int4 z = make_int4(0, 0, 0, 0);
        for (int i = blockIdx.x * 256 + t; i < EN; i += NCH * 256) cz[i] = z;
    }
    int base = blockIdx.x * 1024 + t * 4;
    int s = 0;
    #pragma unroll
    for (int i = 0; i < 4; ++i) { int idx = base + i; if (idx < EN) s += cnt[idx]; }
    sm[t] = s; __syncthreads();
    for (int off = 128; off > 0; off >>= 1) {
        if (t < off) sm[t] += sm[t + off];
        __syncthreads();
    }
    if (t == 0) part[blockIdx.x] = sm[0];
}

// ---------- scan B: redundant global rescan + col_start + ccur, block0 extras ----------
__global__ void k_scanB(const int* __restrict__ cnt, const int* __restrict__ part,
                        const int* __restrict__ rcnt,
                        int* __restrict__ rbase, int* __restrict__ cursor,
                        int* __restrict__ col_start, int* __restrict__ ccur,
                        int4* __restrict__ bk_pack) {
    __shared__ int sm[256];
    __shared__ int sbase[R + 1];
    __shared__ int scnt[R];
    int t = threadIdx.x, bid = blockIdx.x;
    // pass 1: scan global chunk partials (redundant per block, L2-hot 784 B)
    sm[t] = (t < NCH) ? part[t] : 0;
    __syncthreads();
    for (int off = 1; off < 256; off <<= 1) {
        int u = 0; if (t >= off) u = sm[t - off];
        __syncthreads(); sm[t] += u; __syncthreads();
    }
    const int base0 = (bid > 0) ? sm[bid - 1] : 0;
    __syncthreads();                      // protect sm before reuse
    // pass 2: intra-chunk exclusive positions
    int base = bid * 1024 + t * 4;
    int v[4]; int s = 0;
    #pragma unroll
    for (int i = 0; i < 4; ++i) { int idx = base + i; v[i] = (idx < EN) ? cnt[idx] : 0; s += v[i]; }
    sm[t] = s; __syncthreads();
    for (int off = 1; off < 256; off <<= 1) {
        int u = 0; if (t >= off) u = sm[t - off];
        __syncthreads(); sm[t] += u; __syncthreads();
    }
    int ex = ((t > 0) ? sm[t - 1] : 0) + base0;
    #pragma unroll
    for (int i = 0; i < 4; ++i) {
        int idx = base + i;
        if (idx < EN) { col_start[idx] = ex; ex += v[i]; ccur[idx] = 0; }
    }
    // block 0 extras: 16-padded relation bases + bk pad-init
    if (bid == 0) {
        if (t == 0) {
            int acc = 0;
            for (int r = 0; r < R; ++r) {
                sbase[r] = acc; rbase[r] = acc; cursor[r] = acc;
                int c0 = rcnt[r]; scnt[r] = c0;
                acc += (c0 + 15) & ~15;   // 16-aligned bucket regions
            }
            sbase[R] = acc; rbase[R] = acc;
            col_start[EN] = EN;
        }
        __syncthreads();
        // pads: row=0 (safe gather), dst=EN (dump row), coef=0 (no contribution)
        for (int r = 0; r < R; ++r) {
            int ps = sbase[r] + scnt[r], pe = sbase[r + 1];
            for (int i = ps + t; i < pe; i += 256)
                bk_pack[i] = make_int4(0, EN, 0, 0);
        }
    }
}

// ---------- bucket (4 edges/thread, int4/float4 loads) + col-sorted slot + crel ----------
// rsqrt inline from cnt (L2-hot). 4 independent per-edge chains per thread -> MLP.
__global__ void k_bucket(const int* __restrict__ row, const int* __restrict__ col,
                         const int* __restrict__ etype, const float* __restrict__ attr,
                         const int* __restrict__ cnt, const int* __restrict__ col_start,
                         int* __restrict__ cursor, int* __restrict__ ccur,
                         int4* __restrict__ bk_pack, float* __restrict__ crel) {
    __shared__ int lcnt[R];
    __shared__ int lbase[R];
    int t = threadIdx.x;
    if (t < R) lcnt[t] = 0;
    __syncthreads();
    const int e0 = blockIdx.x * 1024 + t * 4;
    int cc[4], rw[4], rr[4], rank[4];
    float av[4], cf[4];
    int ne = 0;
    if (e0 + 3 < EN) {
        int4 c4 = *(const int4*)(col + e0);
        int4 r4 = *(const int4*)(row + e0);
        int4 y4 = *(const int4*)(etype + e0);
        float4 a4 = *(const float4*)(attr + e0);
        cc[0] = c4.x; cc[1] = c4.y; cc[2] = c4.z; cc[3] = c4.w;
        rw[0] = r4.x; rw[1] = r4.y; rw[2] = r4.z; rw[3] = r4.w;
        rr[0] = y4.x; rr[1] = y4.y; rr[2] = y4.z; rr[3] = y4.w;
        av[0] = a4.x; av[1] = a4.y; av[2] = a4.z; av[3] = a4.w;
        ne = 4;
    } else {
        for (int e = e0; e < EN; ++e) {
            int i = e - e0;
            cc[i] = col[e]; rw[i] = row[e]; rr[i] = etype[e]; av[i] = attr[e];
            ++ne;
        }
    }
    #pragma unroll
    for (int i = 0; i < 4; ++i) {
        if (i < ne) {
            rank[i] = atomicAdd(&lcnt[rr[i]], 1);
            int dr = cnt[rw[i]], dc = cnt[cc[i]];
            float a = (dr > 0) ? rsqrtf((float)dr) : 0.f;
            float b = (dc > 0) ? rsqrtf((float)dc) : 0.f;
            cf[i] = av[i] * a * b;
        }
    }
    __syncthreads();
    if (t < R) lbase[t] = lcnt[t] ? atomicAdd(&cursor[t], lcnt[t]) : 0;
    __syncthreads();
    #pragma unroll
    for (int i = 0; i < 4; ++i) {
        if (i < ne) {
            int pos = lbase[rr[i]] + rank[i];                   // padded relation bucket
            int sp = col_start[cc[i]] + atomicAdd(&ccur[cc[i]], 1);  // col-sorted slot
            bk_pack[pos] = make_int4(rw[i], sp, __float_as_int(cf[i]), 0);
            atomicAdd(&crel[cc[i] * 4 + rr[i]], cf[i]);
        }
    }
}

// ================= MFMA GEMM: flat 1-D tile grid over padded buckets =================
// LAYER 2: B-frags = z1 on the fly from crel[srow] (16 B) vs LDS s1/b1; writes msg2.
// LAYER 3: B-frags = z2 on the fly from msg2 segment [col_start[srow],col_start[srow+1])
//          (col-sorted => contiguous; E[deg]=1) + b2 + leaky; writes msg3.
template<int LAYER>
__global__ __launch_bounds__(256)
void k_gemm(const unsigned short* __restrict__ msrc,    // LAYER 3: msg2
            const unsigned short* __restrict__ wsw,
            const int4* __restrict__ bk_pack, const int* __restrict__ rbase,
            const int* __restrict__ col_start,
            const float* __restrict__ crel, const float* __restrict__ s1g,
            const float* __restrict__ b1, const float* __restrict__ b2,
            unsigned short* __restrict__ mdst) {
    const int t = threadIdx.x;
    __shared__ unsigned short xpose[4][16 * 144];   // 18 KB; wave-private regions
    __shared__ float ls1[R * D];
    __shared__ float lb[D];                         // b1 (L2) or b2 (L3)
    if constexpr (LAYER == 2) {
        ls1[t] = s1g[t];
        ls1[t + 256] = s1g[t + 256];
        if (t < D) lb[t] = b1[t];
    } else {
        if (t < D) lb[t] = b2[t];
    }
    __syncthreads();                        // before any wave can early-exit
    const int tile = blockIdx.x * 4 + (t >> 6);
    const int e16 = tile * 16;
    if (e16 >= rbase[R]) return;            // wave-uniform early exit (tail only)
    const int r = (e16 >= rbase[1]) + (e16 >= rbase[2]) + (e16 >= rbase[3]);
    const int l = t & 63, q = l >> 4, n16 = l & 15;
    const int p = e16 + n16;                // always in-bounds (padded buckets)
    const int4 bk = bk_pack[p];             // one 16 B load: {row, dst, coef, -}
    const int srow = bk.x;
    const int dp = bk.y;
    const float cf = __int_as_float(bk.z);

    // B-frags: x[edge][k]; lane covers k = s*32 + q*8 .. +8
    bf16x8 xf[4];
    if constexpr (LAYER == 2) {
        const float4 cr = ((const float4*)crel)[srow];   // 16 B instead of 256 B row
        #pragma unroll
        for (int s = 0; s < 4; ++s) {
            union { unsigned short us[8]; bf16x8 v; } o;
            #pragma unroll
            for (int j = 0; j < 8; ++j) {
                int k = s * 32 + q * 8 + j;
                float xv = lb[k] + cr.x * ls1[k] + cr.y * ls1[D + k]
                         + cr.z * ls1[2 * D + k] + cr.w * ls1[3 * D + k];
                xv = (xv > 0.f) ? xv : NEG * xv;
                o.us[j] = f2bf(xv);
            }
            xf[s] = o.v;
        }
    } else {
        // z2 on the fly: fp32 segment sum over msg2 (pads: srow=0, harmless)
        const int st = col_start[srow], en = col_start[srow + 1];
        float za[32];
        #pragma unroll
        for (int i = 0; i < 32; ++i) za[i] = 0.f;
        for (int p2 = st; p2 < en; ++p2) {
            const unsigned short* mrow = msrc + (size_t)p2 * D + q * 8;
            #pragma unroll
            for (int s = 0; s < 4; ++s) {
                uint4 u = *(const uint4*)(mrow + s * 32);
                za[s * 8 + 0] += bflo(u.x); za[s * 8 + 1] += bfhi(u.x);
                za[s * 8 + 2] += bflo(u.y); za[s * 8 + 3] += bfhi(u.y);
                za[s * 8 + 4] += bflo(u.z); za[s * 8 + 5] += bfhi(u.z);
                za[s * 8 + 6] += bflo(u.w); za[s * 8 + 7] += bfhi(u.w);
            }
        }
        #pragma unroll
        for (int s = 0; s < 4; ++s) {
            union { unsigned short us[8]; bf16x8 v; } o;
            #pragma unroll
            for (int j = 0; j < 8; ++j) {
                float xv = za[s * 8 + j] + lb[s * 32 + q * 8 + j];
                xv = (xv > 0.f) ? xv : NEG * xv;
                o.us[j] = f2bf(xv);
            }
            xf[s] = o.v;
        }
    }

    // A-frags: swizzled W, L1/L2-resident
    const unsigned short* wr = wsw + ((size_t)r * 2048 + l) * 8;

    f32x4 acc[8];
    #pragma unroll
    for (int mt = 0; mt < 8; ++mt) acc[mt] = (f32x4){0.f, 0.f, 0.f, 0.f};

    #pragma unroll
    for (int s = 0; s < 4; ++s) {
        #pragma unroll
        for (int mt = 0; mt < 8; ++mt) {
            bf16x8 wf = *(const bf16x8*)(wr + (size_t)(s * 512 + mt * 64) * 8);
            acc[mt] = __builtin_amdgcn_mfma_f32_16x16x32_bf16(wf, xf[s], acc[mt], 0, 0, 0);
        }
    }

    // epilogue: scale, pack, transpose through wave-private LDS, coalesced store
    unsigned short* lbuf = xpose[t >> 6];
    #pragma unroll
    for (int mt = 0; mt < 8; ++mt) {
        uint2 u;
        u.x = pack2bf(acc[mt].x * cf, acc[mt].y * cf);
        u.y = pack2bf(acc[mt].z * cf, acc[mt].w * cf);
        *(uint2*)&lbuf[n16 * 144 + mt * 16 + q * 4] = u;
    }
    #pragma unroll
    for (int ro = 0; ro < 4; ++ro) {
        int e = ro * 4 + q;
        uint4 v = *(const uint4*)&lbuf[e * 144 + n16 * 8];
        int rdp = __shfl(dp, e);
        *(uint4*)(mdst + (size_t)rdp * D + n16 * 8) = v;
    }
}

// ================= final combine: 2 columns/wave, uint2 loads =================
// dout = (1 + z1(crel) + z2(msg2) + z3(msg3)) * 0.25; z1,z2 fp32 (never materialized).
__global__ void k_agg3(const unsigned* __restrict__ m2, const unsigned* __restrict__ m3,
                       const float* __restrict__ b2v, const float* __restrict__ b3v,
                       const int* __restrict__ col_start,
                       const float* __restrict__ crel, const float* __restrict__ s1g,
                       const float* __restrict__ b1, float* __restrict__ dout) {
    __shared__ float ls1[R * D];
    __shared__ float lb1[D], lb2[D], lb3[D];
    int t = threadIdx.x;
    ls1[t] = s1g[t];
    ls1[t + 256] = s1g[t + 256];
    if (t < D) { lb1[t] = b1[t]; lb2[t] = b2v[t]; lb3[t] = b3v[t]; }
    __syncthreads();
    const int h = t >> 5, l32 = t & 31;     // 8 half-waves -> 8 columns per block
    const uint2* m2v = (const uint2*)m2;
    const uint2* m3v = (const uint2*)m3;
    for (int c = blockIdx.x * 8 + h; c < EN; c += gridDim.x * 8) {
        int st = col_start[c], pe = col_start[c + 1];
        float s2[4] = {0.f, 0.f, 0.f, 0.f};
        float s3[4] = {0.f, 0.f, 0.f, 0.f};
        for (int p = st; p < pe; ++p) {
            uint2 u2 = m2v[(size_t)p * 32 + l32];
            uint2 u3 = m3v[(size_t)p * 32 + l32];
            s2[0] += bflo(u2.x); s2[1] += bfhi(u2.x);
            s2[2] += bflo(u2.y); s2[3] += bfhi(u2.y);
            s3[0] += bflo(u3.x); s3[1] += bfhi(u3.x);
            s3[2] += bflo(u3.y); s3[3] += bfhi(u3.y);
        }
        float4 cr = ((const float4*)crel)[c];   // uniform within half-wave
        int d0 = l32 * 4;
        float o[4];
        #pragma unroll
        for (int j = 0; j < 4; ++j) {
            int d = d0 + j;
            float z2 = s2[j] + lb2[d];
            z2 = (z2 > 0.f) ? z2 : NEG * z2;
            float z3 = s3[j] + lb3[d];
            z3 = (z3 > 0.f) ? z3 : NEG * z3;
            float z1 = lb1[d] + cr.x * ls1[d] + cr.y * ls1[D + d]
                     + cr.z * ls1[2 * D + d] + cr.w * ls1[3 * D + d];
            z1 = (z1 > 0.f) ? z1 : NEG * z1;
            o[j] = (1.f + z1 + z2 + z3) * 0.25f;
        }
        float4 ov = make_float4(o[0], o[1], o[2], o[3]);
        ((float4*)(dout + (size_t)c * D))[l32] = ov;
    }
}

extern "C" void kernel_launch(void* const* d_in, const int* in_sizes, int n_in,
                              void* d_out, int out_size, void* d_ws, size_t ws_size,
                              hipStream_t stream) {
    const int*   eidx = (const int*)d_in[0];     // [2, E]
    const int*   row  = eidx;
    const int*   col  = eidx + EN;
    const int*   etyp = (const int*)d_in[1];
    const float* attr = (const float*)d_in[2];
    const float* w1   = (const float*)d_in[3];
    const float* b1   = (const float*)d_in[4];
    const float* w2   = (const float*)d_in[5];
    const float* b2   = (const float*)d_in[6];
    const float* w3   = (const float*)d_in[7];
    const float* b3   = (const float*)d_in[8];
    float* dout = (float*)d_out;

    // workspace layout (~114 MB; ws is ~409.6 MB per harness poison size)
    char* wsb = (char*)d_ws;
    size_t off = 0;
    unsigned short* msg2 = (unsigned short*)(wsb + off); off += (size_t)(EN + 1) * D * 2 + 512;
    unsigned short* msg3 = (unsigned short*)(wsb + off); off += (size_t)(EN + 1) * D * 2 + 512;
    int*   col_start = (int*)(wsb + off); off += 800032;
    int*   cnt       = (int*)(wsb + off); off += (size_t)EN * 4;
    int*   rcnt      = (int*)(wsb + off); off += 16;          // contiguous after cnt
    float* crel      = (float*)(wsb + off); off += (size_t)EN * 16;
    int4*  bk_pack   = (int4*)(wsb + off); off += (size_t)(EN + 64) * 16;
    unsigned short* w2b = (unsigned short*)(wsb + off); off += 131072;
    unsigned short* w3b = (unsigned short*)(wsb + off); off += 131072;
    int*   part      = (int*)(wsb + off); off += 1024;
    int*   rbase     = (int*)(wsb + off); off += 32;
    int*   cursor    = (int*)(wsb + off); off += 16;
    float* s1        = (float*)(wsb + off); off += (size_t)R * D * 4;
    int*   ccur      = (int*)msg2;   // aliased: msg2 not live until GEMM layer 2

    dim3 blk(256);

    // zero cnt + rcnt only (0.8 MB); crel zeroed inside k_scanA
    hipMemsetAsync(cnt, 0, (size_t)EN * 4 + 16, stream);
    // histogram (ILP-4) + W prep
    k_cntprep<<<NBLKE4 + NPREP, blk, 0, stream>>>(col, etyp, w1, w2, w3,
                                                  cnt, rcnt, w2b, w3b, s1);
    // scans: chunk sums + crel zero, then fused rescan + col_start + ccur + extras
    k_scanA<<<NCH, blk, 0, stream>>>(cnt, part, crel);
    k_scanB<<<NCH, blk, 0, stream>>>(cnt, part, rcnt, rbase, cursor, col_start,
                                     ccur, bk_pack);
    // bucket (ILP-4) + col-sort placement + coef + crel accumulation
    k_bucket<<<NBLKE4, blk, 0, stream>>>(row, col, etyp, attr, cnt, col_start,
                                         cursor, ccur, bk_pack, crel);

    // layers 2,3: flat-tile GEMM (z1, z2 both on the fly) + single final combine
    const int nTiles = ceil_div(EN + 64, 16);
    const int gB = ceil_div(nTiles, 4);              // 3126 blocks
    k_gemm<2><<<gB, blk, 0, stream>>>(nullptr, w2b, bk_pack, rbase, col_start,
                                      crel, s1, b1, b2, msg2);
    k_gemm<3><<<gB, blk, 0, stream>>>(msg2, w3b, bk_pack, rbase, col_start,
                                      crel, s1, b1, b2, msg3);
    k_agg3<<<2048, blk, 0, stream>>>((const unsigned*)msg2, (const unsigned*)msg3,
                                     b2, b3, col_start, crel, s1, b1, dout);
}